// Round 3
// baseline (201.310 us; speedup 1.0000x reference)
//
#include <hip/hip_runtime.h>
#include <hip/hip_bf16.h>

// Stratified max pooling: out[b,c] = max over j with labels[j]==c of values[b,j]
// values: [B, N] fp32, labels: [N] int32, out: [B, C] fp32.
//
// Round 3: atomic-free. One wave per block, lane = row. Stage 64x64 value
// tiles transposed in LDS (coalesced global reads, conflict-free LDS), then
// per column do a plain read-max-write into a wave-private LDS accumulator
// acc[class][row-lane] -- all lanes hit distinct words, single wave => no
// atomics, no barriers. Partials to d_ws, deterministic reduce into d_out.

#define WTPB 64      // threads per block = 1 wave; lane = row
#define JT   64      // columns per tile
#define TPAD 65      // tile leading pad: staging writes 2-way (free), reads stride-1
#define CCAP 128     // max classes on main path
#define NEGINF (-__builtin_huge_valf())

__global__ __launch_bounds__(WTPB) void strat_tpose(
    const float* __restrict__ values, const int* __restrict__ labels,
    float* __restrict__ part, int B, int N, int C, int S, int T) {
    __shared__ float tile[JT * TPAD];    // [col][row] transposed stage
    __shared__ float acc[CCAP * WTPB];   // [class][row-lane], wave-private

    const int lane = threadIdx.x;
    const int s    = blockIdx.x;
    const int rg   = blockIdx.y;
    const int row0 = rg * WTPB;
    const int rmax = min(WTPB, B - row0);

    for (int i = lane; i < C * WTPB; i += WTPB) acc[i] = NEGINF;
    // single wave: DS ops complete in program order; no __syncthreads anywhere.

    for (int t = s; t < T; t += S) {
        const int jc = t * JT + lane;          // my column (lane = col while staging)
        int lab = 0;
        if (jc < N) lab = labels[jc];
        const float* colp = values + (size_t)row0 * N + jc;
        float* tcol = tile + lane * TPAD;

        if (jc < N && rmax == WTPB) {
#pragma unroll
            for (int r = 0; r < WTPB; ++r)
                tcol[r] = colp[(size_t)r * N];          // coalesced 256B per r
        } else {
            for (int r = 0; r < WTPB; ++r)
                tcol[r] = (jc < N && r < rmax) ? colp[(size_t)r * N] : NEGINF;
        }

        // compute: lane = row; per column broadcast label, plain RMW max.
#pragma unroll
        for (int j = 0; j < JT; ++j) {
            const int   c = __builtin_amdgcn_readlane(lab, j);  // j literal -> SALU
            const float v = tile[j * TPAD + lane];              // stride-1, no conflict
            float* a = acc + c * WTPB + lane;                   // distinct word per lane
            const float o = *a;
            *a = fmaxf(o, v);
        }
    }

    // flush wave-private partials (coalesced 256B per class)
    float* dst = part + ((size_t)rg * S + s) * ((size_t)C * WTPB);
    for (int i = lane; i < C * WTPB; i += WTPB) dst[i] = acc[i];
}

// out[b,c] = max over s of part[(rg*S+s)*C*64 + c*64 + l],  b = rg*64+l
__global__ __launch_bounds__(256) void strat_reduce2(
    const float* __restrict__ part, float* __restrict__ out,
    int B, int C, int S, int RG) {
    const int PC = C * WTPB;
    const int i  = blockIdx.x * 256 + threadIdx.x;
    if (i >= RG * PC) return;
    const int rg  = i / PC;
    const int rem = i - rg * PC;
    const int c   = rem >> 6;
    const int l   = rem & 63;
    const int b   = rg * WTPB + l;
    if (b >= B) return;

    const float* p = part + (size_t)rg * S * PC + rem;
    float m0 = NEGINF, m1 = NEGINF, m2 = NEGINF, m3 = NEGINF;
    int s = 0;
    for (; s + 4 <= S; s += 4) {
        m0 = fmaxf(m0, p[(size_t)(s + 0) * PC]);
        m1 = fmaxf(m1, p[(size_t)(s + 1) * PC]);
        m2 = fmaxf(m2, p[(size_t)(s + 2) * PC]);
        m3 = fmaxf(m3, p[(size_t)(s + 3) * PC]);
    }
    for (; s < S; ++s) m0 = fmaxf(m0, p[(size_t)s * PC]);
    out[b * C + c] = fmaxf(fmaxf(m0, m1), fmaxf(m2, m3));
}

// ---------------- fallback (round-1 structure): for C > CCAP etc. ----------

#define TPB   256
#define ROWS  8
#define FCPAD 257
#define ENC_NEG_INF 0x007FFFFFu

__device__ __forceinline__ unsigned enc(float f) {
    unsigned u = __float_as_uint(f);
    return (u & 0x80000000u) ? ~u : (u | 0x80000000u);
}
__device__ __forceinline__ float dec(unsigned u) {
    unsigned b = (u & 0x80000000u) ? (u & 0x7FFFFFFFu) : ~u;
    return __uint_as_float(b);
}

__global__ __launch_bounds__(TPB) void strat_init(unsigned* __restrict__ out_enc, int n) {
    int i = blockIdx.x * TPB + threadIdx.x;
    if (i < n) out_enc[i] = ENC_NEG_INF;
}

__global__ __launch_bounds__(TPB) void strat_main_atomic(
    const float* __restrict__ values, const int* __restrict__ labels,
    unsigned* __restrict__ out_enc, int B, int N, int C, int T) {
    __shared__ unsigned acc[ROWS * FCPAD];
    const int tid  = threadIdx.x;
    const int row0 = blockIdx.y * ROWS;
    const int rmax = min(ROWS, B - row0);

    for (int i = tid; i < ROWS * FCPAD; i += TPB) acc[i] = ENC_NEG_INF;
    __syncthreads();

    const int t = blockIdx.x;
#pragma unroll
    for (int e = 0; e < 4; ++e) {
        const int j = t * 1024 + tid * 4 + e;
        if (j < N) {
            const int c = labels[j];
            for (int r = 0; r < rmax; ++r)
                atomicMax(&acc[r * FCPAD + c],
                          enc(values[(size_t)(row0 + r) * N + j]));
        }
    }
    __syncthreads();
    for (int i = tid; i < rmax * C; i += TPB) {
        const int r = i / C, c = i - r * C;
        atomicMax(&out_enc[(size_t)(row0 + r) * C + c], acc[r * FCPAD + c]);
    }
}

__global__ __launch_bounds__(TPB) void strat_decode(unsigned* __restrict__ buf, int n) {
    int i = blockIdx.x * TPB + threadIdx.x;
    if (i < n) {
        float f = dec(buf[i]);
        ((float*)buf)[i] = f;
    }
}

// ---------------------------------------------------------------------------

extern "C" void kernel_launch(void* const* d_in, const int* in_sizes, int n_in,
                              void* d_out, int out_size, void* d_ws, size_t ws_size,
                              hipStream_t stream) {
    const float* values = (const float*)d_in[0];
    const int*   labels = (const int*)d_in[1];
    const int N  = in_sizes[1];
    const int B  = in_sizes[0] / N;
    const int C  = out_size / B;
    const int T  = (N + JT - 1) / JT;          // 64-col tiles
    const int RG = (B + WTPB - 1) / WTPB;      // 64-row groups

    // Splits: target 768 total blocks (3 per CU, LDS-bound occupancy).
    int S = 768 / (RG > 0 ? RG : 1);
    if (S < 1) S = 1;
    if (S > T) S = T;
    size_t need = (size_t)RG * S * C * WTPB * sizeof(float);
    while (S > 1 && need > ws_size) {
        S >>= 1;
        need = (size_t)RG * S * C * WTPB * sizeof(float);
    }

    const bool main_ok = (C <= CCAP) && (need <= ws_size) && (S >= 1);

    if (main_ok) {
        float* part = (float*)d_ws;
        dim3 grid(S, RG);
        strat_tpose<<<grid, WTPB, 0, stream>>>(values, labels, part, B, N, C, S, T);
        const int outs = RG * C * WTPB;
        strat_reduce2<<<(outs + 255) / 256, 256, 0, stream>>>(
            part, (float*)d_out, B, C, S, RG);
    } else {
        unsigned* out_enc = (unsigned*)d_out;
        const int init_blocks = (out_size + TPB - 1) / TPB;
        strat_init<<<init_blocks, TPB, 0, stream>>>(out_enc, out_size);
        dim3 grid((N + 1023) / 1024, (B + ROWS - 1) / ROWS);
        strat_main_atomic<<<grid, TPB, 0, stream>>>(values, labels, out_enc, B, N, C,
                                                    (N + 1023) / 1024);
        strat_decode<<<init_blocks, TPB, 0, stream>>>(out_enc, out_size);
    }
}

// Round 4
// 174.006 us; speedup vs baseline: 1.1569x; 1.1569x over previous
//
#include <hip/hip_runtime.h>
#include <hip/hip_bf16.h>

// Stratified max pooling: out[b,c] = max over j with labels[j]==c of values[b,j]
// values: [B, N] fp32, labels: [N] int32, out: [B, C] fp32.
//
// Round 4: fire-and-forget LDS atomics (no read-max-write latency chain).
// Block = 256 threads, lane = column. acc[C][65] u32 (monotone-encoded fp32);
// stride 65 spreads banks (stride 64 would put all lanes of one ds_max in one
// bank). Per column: 64 coalesced row loads -> enc -> 64 ds_max_u32 with
// immediate offsets. No LDS reads, no staging, no hot-loop barriers.
// Partials (encoded) to d_ws; deterministic reduce+decode into d_out.

#define TPBS 256
#define COLS 256                 // columns per block-tile (== TPBS)
#define ENC_NEG_INF 0x007FFFFFu  // enc(-inf)

__device__ __forceinline__ unsigned enc(float f) {
    unsigned u = __float_as_uint(f);
    return (u & 0x80000000u) ? ~u : (u | 0x80000000u);
}
__device__ __forceinline__ float dec(unsigned u) {
    unsigned b = (u & 0x80000000u) ? (u & 0x7FFFFFFFu) : ~u;
    return __uint_as_float(b);
}

__global__ __launch_bounds__(TPBS) void strat_scat(
    const float* __restrict__ values, const int* __restrict__ labels,
    unsigned* __restrict__ part, int B, int N, int C, int S, int T) {
    extern __shared__ unsigned acc[];   // [C][65]: acc[c*65 + r], r = row-in-group

    const int tid  = threadIdx.x;
    const int s    = blockIdx.x;
    const int rg   = blockIdx.y;
    const int row0 = rg * 64;
    const int rmax = min(64, B - row0);
    const int CW   = C * 65;

    for (int i = tid; i < CW; i += TPBS) acc[i] = ENC_NEG_INF;
    __syncthreads();

    for (int t = s; t < T; t += S) {
        const int jc = t * COLS + tid;
        if (jc < N) {
            const unsigned lab = (unsigned)labels[jc];
            unsigned* a = acc + lab * 65;
            const float* col = values + (size_t)row0 * N + jc;
            if (rmax == 64) {
#pragma unroll
                for (int rb = 0; rb < 64; rb += 16) {
                    float v[16];
#pragma unroll
                    for (int r = 0; r < 16; ++r)
                        v[r] = col[(size_t)(rb + r) * N];   // 256B coalesced per instr
#pragma unroll
                    for (int r = 0; r < 16; ++r)
                        atomicMax(&a[rb + r], enc(v[r]));   // ds_max_u32, no return
                }
            } else {
                for (int r = 0; r < rmax; ++r)
                    atomicMax(&a[r], enc(col[(size_t)r * N]));
            }
        }
    }
    __syncthreads();

    // Flush encoded partials: part[(rg*S + s)][c*64 + r]
    unsigned* dst = part + (size_t)(rg * S + s) * ((size_t)C * 64);
    for (int i = tid; i < C * 64; i += TPBS)
        dst[i] = acc[(i >> 6) * 65 + (i & 63)];
}

// out[b,c] = dec(max over s of part[(rg*S+s)*C*64 + c*64 + l]), b = rg*64 + l
__global__ __launch_bounds__(256) void strat_red(
    const unsigned* __restrict__ part, float* __restrict__ out,
    int B, int C, int S, int RG) {
    const int PC = C * 64;
    const int i  = blockIdx.x * 256 + threadIdx.x;
    if (i >= RG * PC) return;
    const int rg  = i / PC;
    const int rem = i - rg * PC;
    const int c   = rem >> 6;
    const int l   = rem & 63;
    const int b   = rg * 64 + l;

    const unsigned* p = part + (size_t)rg * S * PC + rem;
    unsigned m0 = ENC_NEG_INF, m1 = ENC_NEG_INF, m2 = ENC_NEG_INF, m3 = ENC_NEG_INF;
    unsigned m4 = ENC_NEG_INF, m5 = ENC_NEG_INF, m6 = ENC_NEG_INF, m7 = ENC_NEG_INF;
    int s = 0;
    for (; s + 8 <= S; s += 8) {
        m0 = max(m0, p[(size_t)(s + 0) * PC]);
        m1 = max(m1, p[(size_t)(s + 1) * PC]);
        m2 = max(m2, p[(size_t)(s + 2) * PC]);
        m3 = max(m3, p[(size_t)(s + 3) * PC]);
        m4 = max(m4, p[(size_t)(s + 4) * PC]);
        m5 = max(m5, p[(size_t)(s + 5) * PC]);
        m6 = max(m6, p[(size_t)(s + 6) * PC]);
        m7 = max(m7, p[(size_t)(s + 7) * PC]);
    }
    for (; s < S; ++s) m0 = max(m0, p[(size_t)s * PC]);
    m0 = max(max(max(m0, m1), max(m2, m3)), max(max(m4, m5), max(m6, m7)));
    if (b < B) out[b * C + c] = dec(m0);
}

// ---------------- fallback (round-1 structure): odd shapes ------------------

#define TPB   256
#define ROWS  8
#define FCPAD 257

__global__ __launch_bounds__(TPB) void strat_init(unsigned* __restrict__ out_enc, int n) {
    int i = blockIdx.x * TPB + threadIdx.x;
    if (i < n) out_enc[i] = ENC_NEG_INF;
}

__global__ __launch_bounds__(TPB) void strat_main_atomic(
    const float* __restrict__ values, const int* __restrict__ labels,
    unsigned* __restrict__ out_enc, int B, int N, int C, int T) {
    __shared__ unsigned acc[ROWS * FCPAD];
    const int tid  = threadIdx.x;
    const int row0 = blockIdx.y * ROWS;
    const int rmax = min(ROWS, B - row0);

    for (int i = tid; i < ROWS * FCPAD; i += TPB) acc[i] = ENC_NEG_INF;
    __syncthreads();

    const int t = blockIdx.x;
#pragma unroll
    for (int e = 0; e < 4; ++e) {
        const int j = t * 1024 + tid * 4 + e;
        if (j < N) {
            const int c = labels[j];
            for (int r = 0; r < rmax; ++r)
                atomicMax(&acc[r * FCPAD + c],
                          enc(values[(size_t)(row0 + r) * N + j]));
        }
    }
    __syncthreads();
    for (int i = tid; i < rmax * C; i += TPB) {
        const int r = i / C, c = i - r * C;
        atomicMax(&out_enc[(size_t)(row0 + r) * C + c], acc[r * FCPAD + c]);
    }
}

__global__ __launch_bounds__(TPB) void strat_decode(unsigned* __restrict__ buf, int n) {
    int i = blockIdx.x * TPB + threadIdx.x;
    if (i < n) {
        float f = dec(buf[i]);
        ((float*)buf)[i] = f;
    }
}

// ---------------------------------------------------------------------------

extern "C" void kernel_launch(void* const* d_in, const int* in_sizes, int n_in,
                              void* d_out, int out_size, void* d_ws, size_t ws_size,
                              hipStream_t stream) {
    const float* values = (const float*)d_in[0];
    const int*   labels = (const int*)d_in[1];
    const int N  = in_sizes[1];
    const int B  = in_sizes[0] / N;
    const int C  = out_size / B;
    const int T  = (N + COLS - 1) / COLS;      // 256-col tiles
    const int RG = (B + 63) / 64;              // 64-row groups

    // Tiles per block k targets ~1024 blocks (4/CU); S = split count.
    long total = (long)T * RG;
    int k = (int)((total + 1023) / 1024);
    if (k < 1) k = 1;
    int S = (T + k - 1) / k;
    size_t need = (size_t)RG * S * C * 64 * sizeof(unsigned);
    while (S > 1 && need > ws_size) {
        S = (S + 1) / 2;
        need = (size_t)RG * S * C * 64 * sizeof(unsigned);
    }

    const size_t lds = (size_t)C * 65 * sizeof(unsigned);
    const bool main_ok = (lds <= 64 * 1024) && (need <= ws_size) && (S >= 1);

    if (main_ok) {
        unsigned* part = (unsigned*)d_ws;
        dim3 grid(S, RG);
        strat_scat<<<grid, TPBS, lds, stream>>>(values, labels, part, B, N, C, S, T);
        const int outs = RG * C * 64;
        strat_red<<<(outs + 255) / 256, 256, 0, stream>>>(
            part, (float*)d_out, B, C, S, RG);
    } else {
        unsigned* out_enc = (unsigned*)d_out;
        const int init_blocks = (out_size + TPB - 1) / TPB;
        strat_init<<<init_blocks, TPB, 0, stream>>>(out_enc, out_size);
        dim3 grid((N + 1023) / 1024, (B + ROWS - 1) / ROWS);
        strat_main_atomic<<<grid, TPB, 0, stream>>>(values, labels, out_enc, B, N, C,
                                                    (N + 1023) / 1024);
        strat_decode<<<init_blocks, TPB, 0, stream>>>(out_enc, out_size);
    }
}

// Round 5
// 165.643 us; speedup vs baseline: 1.2153x; 1.0505x over previous
//
#include <hip/hip_runtime.h>
#include <hip/hip_bf16.h>

// Stratified max pooling: out[b,c] = max over j with labels[j]==c of values[b,j]
// values: [B, N] fp32, labels: [N] int32, out: [B, C] fp32.
//
// Round 5: same fire-and-forget ds_max scatter, restructured for overlap:
//  - 512-thread blocks (8 waves) share one acc[C][65]  -> 24 waves/CU resident
//  - rolling 16-row load batches pipelined against the atomics
//  - two-stage deterministic reduce (no 391-deep serial chains, no 50-block
//    under-occupancy)

#define TPBS 512
#define COLS 512                 // columns per block (== TPBS)
#define SB   16                  // reduce stage-A sub-chunks
#define ENC_NEG_INF 0x007FFFFFu  // enc(-inf)

__device__ __forceinline__ unsigned enc(float f) {
    unsigned u = __float_as_uint(f);
    return (u & 0x80000000u) ? ~u : (u | 0x80000000u);
}
__device__ __forceinline__ float dec(unsigned u) {
    unsigned b = (u & 0x80000000u) ? (u & 0x7FFFFFFFu) : ~u;
    return __uint_as_float(b);
}

// grid = (S, RG); block t owns columns [t*512, t*512+512) x rows [rg*64, +64)
__global__ __launch_bounds__(TPBS) void strat_scat(
    const float* __restrict__ values, const int* __restrict__ labels,
    unsigned* __restrict__ part, int B, int N, int C, int S) {
    extern __shared__ unsigned acc[];   // [C][65]

    const int tid  = threadIdx.x;
    const int t    = blockIdx.x;
    const int rg   = blockIdx.y;
    const int row0 = rg * 64;
    const int rmax = min(64, B - row0);
    const int CW   = C * 65;

    for (int i = tid; i < CW; i += TPBS) acc[i] = ENC_NEG_INF;
    __syncthreads();

    const int jc = t * COLS + tid;
    if (jc < N) {
        const unsigned lab = (unsigned)labels[jc];
        unsigned* a = acc + lab * 65;
        const float* col = values + (size_t)row0 * N + jc;

        if (rmax == 64) {
            // rolling pipeline: 4 batches of 16 rows; load b+1 while ds_max b
            float v[2][16];
#pragma unroll
            for (int r = 0; r < 16; ++r) v[0][r] = col[(size_t)r * N];
#pragma unroll
            for (int b = 0; b < 4; ++b) {
                const int cur = b & 1;
                if (b < 3) {
#pragma unroll
                    for (int r = 0; r < 16; ++r)
                        v[cur ^ 1][r] = col[(size_t)((b + 1) * 16 + r) * N];
                }
#pragma unroll
                for (int r = 0; r < 16; ++r)
                    atomicMax(&a[b * 16 + r], enc(v[cur][r]));  // ds_max_u32
            }
        } else {
            for (int r = 0; r < rmax; ++r)
                atomicMax(&a[r], enc(col[(size_t)r * N]));
        }
    }
    __syncthreads();

    // flush: part[(rg*S + t)][c*64 + r]
    unsigned* dst = part + (size_t)(rg * S + t) * ((size_t)C * 64);
    for (int i = tid; i < C * 64; i += TPBS)
        dst[i] = acc[(i >> 6) * 65 + (i & 63)];
}

// stage A: mid[sb][rg*PC + q] = max over s in sb-chunk of part[(rg*S+s)*PC + q]
__global__ __launch_bounds__(256) void strat_redA(
    const unsigned* __restrict__ part, unsigned* __restrict__ mid,
    int PC, int S, int RG) {
    const int total = RG * PC * SB;
    const int i = blockIdx.x * 256 + threadIdx.x;
    if (i >= total) return;
    const int sb  = i / (RG * PC);
    const int rem = i - sb * (RG * PC);
    const int rg  = rem / PC;
    const int q   = rem - rg * PC;

    const int chunk = (S + SB - 1) / SB;
    const int s0 = sb * chunk;
    const int s1 = min(S, s0 + chunk);

    const unsigned* p = part + ((size_t)rg * S) * PC + q;
    unsigned m0 = ENC_NEG_INF, m1 = ENC_NEG_INF, m2 = ENC_NEG_INF, m3 = ENC_NEG_INF;
    int s = s0;
    for (; s + 4 <= s1; s += 4) {
        m0 = max(m0, p[(size_t)(s + 0) * PC]);
        m1 = max(m1, p[(size_t)(s + 1) * PC]);
        m2 = max(m2, p[(size_t)(s + 2) * PC]);
        m3 = max(m3, p[(size_t)(s + 3) * PC]);
    }
    for (; s < s1; ++s) m0 = max(m0, p[(size_t)s * PC]);
    mid[i] = max(max(m0, m1), max(m2, m3));
}

// stage B: out[b,c] = dec(max over sb of mid[sb][rg*PC + c*64 + l]), b=rg*64+l
__global__ __launch_bounds__(256) void strat_redB(
    const unsigned* __restrict__ mid, float* __restrict__ out,
    int B, int C, int RG) {
    const int PC = C * 64;
    const int i = blockIdx.x * 256 + threadIdx.x;
    if (i >= RG * PC) return;
    unsigned m = ENC_NEG_INF;
#pragma unroll
    for (int sb = 0; sb < SB; ++sb) m = max(m, mid[(size_t)sb * RG * PC + i]);
    const int rg = i / PC;
    const int q  = i - rg * PC;
    const int c  = q >> 6;
    const int l  = q & 63;
    const int b  = rg * 64 + l;
    if (b < B) out[b * C + c] = dec(m);
}

// ---------------- fallback (round-1 structure): odd shapes ------------------

#define TPB   256
#define ROWS  8
#define FCPAD 257

__global__ __launch_bounds__(TPB) void strat_init(unsigned* __restrict__ out_enc, int n) {
    int i = blockIdx.x * TPB + threadIdx.x;
    if (i < n) out_enc[i] = ENC_NEG_INF;
}

__global__ __launch_bounds__(TPB) void strat_main_atomic(
    const float* __restrict__ values, const int* __restrict__ labels,
    unsigned* __restrict__ out_enc, int B, int N, int C, int T) {
    __shared__ unsigned acc[ROWS * FCPAD];
    const int tid  = threadIdx.x;
    const int row0 = blockIdx.y * ROWS;
    const int rmax = min(ROWS, B - row0);

    for (int i = tid; i < ROWS * FCPAD; i += TPB) acc[i] = ENC_NEG_INF;
    __syncthreads();

    const int t = blockIdx.x;
#pragma unroll
    for (int e = 0; e < 4; ++e) {
        const int j = t * 1024 + tid * 4 + e;
        if (j < N) {
            const int c = labels[j];
            for (int r = 0; r < rmax; ++r)
                atomicMax(&acc[r * FCPAD + c],
                          enc(values[(size_t)(row0 + r) * N + j]));
        }
    }
    __syncthreads();
    for (int i = tid; i < rmax * C; i += TPB) {
        const int r = i / C, c = i - r * C;
        atomicMax(&out_enc[(size_t)(row0 + r) * C + c], acc[r * FCPAD + c]);
    }
}

__global__ __launch_bounds__(TPB) void strat_decode(unsigned* __restrict__ buf, int n) {
    int i = blockIdx.x * TPB + threadIdx.x;
    if (i < n) {
        float f = dec(buf[i]);
        ((float*)buf)[i] = f;
    }
}

// ---------------------------------------------------------------------------

extern "C" void kernel_launch(void* const* d_in, const int* in_sizes, int n_in,
                              void* d_out, int out_size, void* d_ws, size_t ws_size,
                              hipStream_t stream) {
    const float* values = (const float*)d_in[0];
    const int*   labels = (const int*)d_in[1];
    const int N  = in_sizes[1];
    const int B  = in_sizes[0] / N;
    const int C  = out_size / B;
    const int RG = (B + 63) / 64;
    const int PC = C * 64;
    const int S  = (N + COLS - 1) / COLS;   // one 512-col tile per block

    const size_t part_bytes = (size_t)RG * S * PC * sizeof(unsigned);
    const size_t mid_off    = (part_bytes + 255) & ~(size_t)255;
    const size_t mid_bytes  = (size_t)SB * RG * PC * sizeof(unsigned);
    const size_t lds        = (size_t)C * 65 * sizeof(unsigned);

    const bool main_ok = (lds <= 64 * 1024) && (mid_off + mid_bytes <= ws_size);

    if (main_ok) {
        unsigned* part = (unsigned*)d_ws;
        unsigned* mid  = (unsigned*)((char*)d_ws + mid_off);

        dim3 grid(S, RG);
        strat_scat<<<grid, TPBS, lds, stream>>>(values, labels, part, B, N, C, S);

        const int totalA = RG * PC * SB;
        strat_redA<<<(totalA + 255) / 256, 256, 0, stream>>>(part, mid, PC, S, RG);

        const int totalB = RG * PC;
        strat_redB<<<(totalB + 255) / 256, 256, 0, stream>>>(mid, (float*)d_out, B, C, RG);
    } else {
        unsigned* out_enc = (unsigned*)d_out;
        const int init_blocks = (out_size + TPB - 1) / TPB;
        strat_init<<<init_blocks, TPB, 0, stream>>>(out_enc, out_size);
        dim3 grid((N + 1023) / 1024, (B + ROWS - 1) / ROWS);
        strat_main_atomic<<<grid, TPB, 0, stream>>>(values, labels, out_enc, B, N, C,
                                                    (N + 1023) / 1024);
        strat_decode<<<init_blocks, TPB, 0, stream>>>(out_enc, out_size);
    }
}

// Round 6
// 164.282 us; speedup vs baseline: 1.2254x; 1.0083x over previous
//
#include <hip/hip_runtime.h>
#include <hip/hip_bf16.h>

// Stratified max pooling: out[b,c] = max over j with labels[j]==c of values[b,j]
// values: [B, N] fp32, labels: [N] int32, out: [B, C] fp32.
//
// Round 6: NO LDS atomics (rounds 1/2/4/5 all saturated the LDS-atomic pipe at
// ~1 lane-op/cyc/CU ~= 42 us for 25.6M ops). Structure: lane = row, waves own
// disjoint class quarters (c&3 == wave), rows disjoint per lane -> plain fp32
// read-max-write with zero hazards. 64x64 tiles staged transposed in LDS by
// all 4 waves (coalesced global loads). 3 blocks/CU (49.4 KB LDS) = 12
// waves/CU for latency hiding. Partials plain fp32; two-stage reduce.

#define TPBS 256                  // 4 waves
#define QMAX 32                   // max classes per wave quarter (C <= 128)
#define SB   16                   // reduce stage-A sub-chunks
#define NEGINF (-__builtin_huge_valf())

__global__ __launch_bounds__(TPBS) void strat_scat(
    const float* __restrict__ values, const int* __restrict__ labels,
    float* __restrict__ part, int B, int N, int C, int S, int T) {
    __shared__ float tile[64 * 65];          // [col][row]: tile[col*65 + row]
    __shared__ float acc[4 * QMAX * 64];     // wave-private: acc[w*2048 + lc*64 + lane]

    const int tid  = threadIdx.x;
    const int wave = tid >> 6;
    const int lane = tid & 63;
    const int s    = blockIdx.x;
    const int rg   = blockIdx.y;
    const int row0 = rg * 64;
    const int rmax = min(64, B - row0);

    for (int i = tid; i < 4 * QMAX * 64; i += TPBS) acc[i] = NEGINF;
    __syncthreads();

    float* myacc = acc + wave * (QMAX * 64);

    for (int t = s; t < T; t += S) {
        const int jc = t * 64 + lane;        // my column while staging
        int lab = 0;
        if (jc < N) lab = labels[jc];

        // ---- stage: wave w loads rows [w*16, w*16+16) for all 64 cols ----
        float* tcol = tile + lane * 65;
        if (jc < N && rmax == 64) {
            const float* colp = values + (size_t)row0 * N + jc;
#pragma unroll
            for (int rr = 0; rr < 16; ++rr) {
                const int r = wave * 16 + rr;
                tcol[r] = colp[(size_t)r * N];   // 256B coalesced per instr
            }
        } else {
#pragma unroll
            for (int rr = 0; rr < 16; ++rr) {
                const int r = wave * 16 + rr;
                tcol[r] = (jc < N && r < rmax)
                              ? values[(size_t)(row0 + r) * N + jc] : NEGINF;
            }
        }
        __syncthreads();

        // ---- consume: lane = row; wave handles classes with (c&3)==wave ----
        unsigned long long mask = __ballot(jc < N && (lab & 3) == wave);
        while (mask) {
            const int j = __ffsll((long long)mask) - 1;
            mask &= mask - 1;
            const int c = __builtin_amdgcn_readlane(lab, j);   // wave-uniform
            const float v = tile[j * 65 + lane];               // conflict-free
            const int idx = (c >> 2) * 64 + lane;              // lc*64 + row
            myacc[idx] = fmaxf(myacc[idx], v);                 // no hazard
        }
        __syncthreads();   // protect tile before next stage
    }

    // ---- flush: wave writes its classes; coalesced 256B per class ----
    float* dst = part + (size_t)(rg * S + s) * ((size_t)C * 64);
    const int Q = (C + 3) >> 2;
    for (int lc = 0; lc < Q; ++lc) {
        const int c = lc * 4 + wave;
        if (c < C) dst[c * 64 + lane] = myacc[lc * 64 + lane];
    }
}

// stage A: mid[sb][rg*PC + q] = max over s in sb-chunk of part[(rg*S+s)*PC + q]
__global__ __launch_bounds__(256) void strat_redA(
    const float* __restrict__ part, float* __restrict__ mid,
    int PC, int S, int RG) {
    const int total = RG * PC * SB;
    const int i = blockIdx.x * 256 + threadIdx.x;
    if (i >= total) return;
    const int sb  = i / (RG * PC);
    const int rem = i - sb * (RG * PC);
    const int rg  = rem / PC;
    const int q   = rem - rg * PC;

    const int chunk = (S + SB - 1) / SB;
    const int s0 = sb * chunk;
    const int s1 = min(S, s0 + chunk);

    const float* p = part + ((size_t)rg * S) * PC + q;
    float m0 = NEGINF, m1 = NEGINF, m2 = NEGINF, m3 = NEGINF;
    int s = s0;
    for (; s + 4 <= s1; s += 4) {
        m0 = fmaxf(m0, p[(size_t)(s + 0) * PC]);
        m1 = fmaxf(m1, p[(size_t)(s + 1) * PC]);
        m2 = fmaxf(m2, p[(size_t)(s + 2) * PC]);
        m3 = fmaxf(m3, p[(size_t)(s + 3) * PC]);
    }
    for (; s < s1; ++s) m0 = fmaxf(m0, p[(size_t)s * PC]);
    mid[i] = fmaxf(fmaxf(m0, m1), fmaxf(m2, m3));
}

// stage B: out[b,c] = max over sb of mid[sb][rg*PC + c*64 + l], b = rg*64+l
__global__ __launch_bounds__(256) void strat_redB(
    const float* __restrict__ mid, float* __restrict__ out,
    int B, int C, int RG) {
    const int PC = C * 64;
    const int i = blockIdx.x * 256 + threadIdx.x;
    if (i >= RG * PC) return;
    float m = NEGINF;
#pragma unroll
    for (int sb = 0; sb < SB; ++sb) m = fmaxf(m, mid[(size_t)sb * RG * PC + i]);
    const int rg = i / PC;
    const int q  = i - rg * PC;
    const int c  = q >> 6;
    const int l  = q & 63;
    const int b  = rg * 64 + l;
    if (b < B) out[b * C + c] = m;
}

// ---------------- fallback (round-1 structure): odd shapes ------------------

#define TPB   256
#define ROWS  8
#define FCPAD 257
#define ENC_NEG_INF 0x007FFFFFu

__device__ __forceinline__ unsigned enc(float f) {
    unsigned u = __float_as_uint(f);
    return (u & 0x80000000u) ? ~u : (u | 0x80000000u);
}
__device__ __forceinline__ float dec(unsigned u) {
    unsigned b = (u & 0x80000000u) ? (u & 0x7FFFFFFFu) : ~u;
    return __uint_as_float(b);
}

__global__ __launch_bounds__(TPB) void strat_init(unsigned* __restrict__ out_enc, int n) {
    int i = blockIdx.x * TPB + threadIdx.x;
    if (i < n) out_enc[i] = ENC_NEG_INF;
}

__global__ __launch_bounds__(TPB) void strat_main_atomic(
    const float* __restrict__ values, const int* __restrict__ labels,
    unsigned* __restrict__ out_enc, int B, int N, int C, int T) {
    __shared__ unsigned acc[ROWS * FCPAD];
    const int tid  = threadIdx.x;
    const int row0 = blockIdx.y * ROWS;
    const int rmax = min(ROWS, B - row0);

    for (int i = tid; i < ROWS * FCPAD; i += TPB) acc[i] = ENC_NEG_INF;
    __syncthreads();

    const int t = blockIdx.x;
#pragma unroll
    for (int e = 0; e < 4; ++e) {
        const int j = t * 1024 + tid * 4 + e;
        if (j < N) {
            const int c = labels[j];
            for (int r = 0; r < rmax; ++r)
                atomicMax(&acc[r * FCPAD + c],
                          enc(values[(size_t)(row0 + r) * N + j]));
        }
    }
    __syncthreads();
    for (int i = tid; i < rmax * C; i += TPB) {
        const int r = i / C, c = i - r * C;
        atomicMax(&out_enc[(size_t)(row0 + r) * C + c], acc[r * FCPAD + c]);
    }
}

__global__ __launch_bounds__(TPB) void strat_decode(unsigned* __restrict__ buf, int n) {
    int i = blockIdx.x * TPB + threadIdx.x;
    if (i < n) {
        float f = dec(buf[i]);
        ((float*)buf)[i] = f;
    }
}

// ---------------------------------------------------------------------------

extern "C" void kernel_launch(void* const* d_in, const int* in_sizes, int n_in,
                              void* d_out, int out_size, void* d_ws, size_t ws_size,
                              hipStream_t stream) {
    const float* values = (const float*)d_in[0];
    const int*   labels = (const int*)d_in[1];
    const int N  = in_sizes[1];
    const int B  = in_sizes[0] / N;
    const int C  = out_size / B;
    const int RG = (B + 63) / 64;
    const int PC = C * 64;
    const int T  = (N + 63) / 64;           // 64-col tiles

    int S = 384;                             // 768 blocks at RG=2 (3/CU)
    if (S > T) S = T;

    const size_t part_bytes = (size_t)RG * S * PC * sizeof(float);
    const size_t mid_off    = (part_bytes + 255) & ~(size_t)255;
    const size_t mid_bytes  = (size_t)SB * RG * PC * sizeof(float);

    const bool main_ok = (C <= 4 * QMAX) && (mid_off + mid_bytes <= ws_size);

    if (main_ok) {
        float* part = (float*)d_ws;
        float* mid  = (float*)((char*)d_ws + mid_off);

        dim3 grid(S, RG);
        strat_scat<<<grid, TPBS, 0, stream>>>(values, labels, part, B, N, C, S, T);

        const int totalA = RG * PC * SB;
        strat_redA<<<(totalA + 255) / 256, 256, 0, stream>>>(part, mid, PC, S, RG);

        const int totalB = RG * PC;
        strat_redB<<<(totalB + 255) / 256, 256, 0, stream>>>(mid, (float*)d_out, B, C, RG);
    } else {
        unsigned* out_enc = (unsigned*)d_out;
        const int init_blocks = (out_size + TPB - 1) / TPB;
        strat_init<<<init_blocks, TPB, 0, stream>>>(out_enc, out_size);
        dim3 grid((N + 1023) / 1024, (B + ROWS - 1) / ROWS);
        strat_main_atomic<<<grid, TPB, 0, stream>>>(values, labels, out_enc, B, N, C,
                                                    (N + 1023) / 1024);
        strat_decode<<<init_blocks, TPB, 0, stream>>>(out_enc, out_size);
    }
}

// Round 7
// 146.243 us; speedup vs baseline: 1.3766x; 1.1234x over previous
//
#include <hip/hip_runtime.h>
#include <hip/hip_bf16.h>

// Stratified max pooling: out[b,c] = max over j with labels[j]==c of values[b,j]
// values: [B, N] fp32, labels: [N] int32, out: [B, C] fp32.
//
// Round 7 "stream": decisive test of the global-load path. Six prior
// structures all read values at ~2.2 TB/s effective regardless of atomics /
// conflicts / occupancy. This kernel is maximally fill-like: contiguous
// nontemporal dwordx4 reads of a flat span within one row, u8-packed labels,
// full occupancy (8 blocks/CU, 32 waves/CU), quadrant-replicated 2KB LDS acc
// (near-zero same-instr conflicts), fire-and-forget ds_max, no hot barriers.

#define TPBS 256
#define SMAX 16                  // column splits per row
#define ENC_NEG_INF 0x007FFFFFu  // enc(-inf)

typedef float f4 __attribute__((ext_vector_type(4)));

__device__ __forceinline__ unsigned enc32(unsigned u) {
    // monotone float->uint: neg -> ~u, pos -> u|0x80000000  (branchless)
    return u ^ ((unsigned)(((int)u) >> 31) | 0x80000000u);
}
__device__ __forceinline__ float dec32(unsigned u) {
    unsigned b = u ^ (~(unsigned)(((int)u) >> 31) | 0x80000000u);
    return __uint_as_float(b);
}

// pack labels to u8 (valid: C <= 128 on main path)
__global__ __launch_bounds__(TPBS) void strat_lab8(
    const int* __restrict__ labels, unsigned char* __restrict__ l8, int N) {
    int i = blockIdx.x * TPBS + threadIdx.x;
    if (i < N) l8[i] = (unsigned char)labels[i];
}

// grid = S*B blocks; block = (s, b): flat span [s*SPAN, +SPAN) of row b.
__global__ __launch_bounds__(TPBS) void strat_stream(
    const float* __restrict__ values, const unsigned char* __restrict__ l8,
    unsigned* __restrict__ part, int B, int N, int C, int S, int SPAN, int CPAD) {
    extern __shared__ unsigned acc[];   // [4][CPAD] quadrant-replicated

    const int tid = threadIdx.x;
    const int blk = blockIdx.x;
    const int s   = blk % S;
    const int b   = blk / S;

    for (int i = tid; i < 4 * CPAD; i += TPBS) acc[i] = ENC_NEG_INF;
    __syncthreads();

    const int off0 = s * SPAN;
    const int len  = min(SPAN, N - off0);
    if (len > 0) {
        unsigned* qacc = acc + ((tid & 63) >> 4) * CPAD;  // lane quadrant
        const f4* vp = (const f4*)(values + (size_t)b * N + off0);
        const uchar4* lp = (const uchar4*)(l8 + off0);
        const int nv = len >> 2;

        for (int i = tid; i < nv; i += TPBS) {
            f4 v = __builtin_nontemporal_load(vp + i);    // 1KB contiguous/instr
            uchar4 L = lp[i];                             // L2/L3-hot
            atomicMax(&qacc[L.x], enc32(__float_as_uint(v.x)));
            atomicMax(&qacc[L.y], enc32(__float_as_uint(v.y)));
            atomicMax(&qacc[L.z], enc32(__float_as_uint(v.z)));
            atomicMax(&qacc[L.w], enc32(__float_as_uint(v.w)));
        }
        for (int i = (nv << 2) + tid; i < len; i += TPBS) {
            atomicMax(&qacc[l8[off0 + i]],
                      enc32(__float_as_uint(values[(size_t)b * N + off0 + i])));
        }
    }
    __syncthreads();

    // flush: max over 4 quadrants -> part[s][b][c]
    unsigned* dst = part + (size_t)s * B * C + (size_t)b * C;
    for (int c = tid; c < C; c += TPBS) {
        unsigned m = max(max(acc[c], acc[CPAD + c]),
                         max(acc[2 * CPAD + c], acc[3 * CPAD + c]));
        dst[c] = m;
    }
}

// out[i] = dec(max over s of part[s*BC + i])
__global__ __launch_bounds__(TPBS) void strat_red(
    const unsigned* __restrict__ part, float* __restrict__ out, int BC, int S) {
    const int i = blockIdx.x * TPBS + threadIdx.x;
    if (i >= BC) return;
    const unsigned* p = part + i;
    unsigned m0 = ENC_NEG_INF, m1 = ENC_NEG_INF, m2 = ENC_NEG_INF, m3 = ENC_NEG_INF;
    int s = 0;
    for (; s + 4 <= S; s += 4) {
        m0 = max(m0, p[(size_t)(s + 0) * BC]);
        m1 = max(m1, p[(size_t)(s + 1) * BC]);
        m2 = max(m2, p[(size_t)(s + 2) * BC]);
        m3 = max(m3, p[(size_t)(s + 3) * BC]);
    }
    for (; s < S; ++s) m0 = max(m0, p[(size_t)s * BC]);
    out[i] = dec32(max(max(m0, m1), max(m2, m3)));
}

// ---------------- fallback (round-1 structure): odd shapes ------------------

#define TPB   256
#define ROWS  8
#define FCPAD 257

__device__ __forceinline__ unsigned encf(float f) {
    return enc32(__float_as_uint(f));
}

__global__ __launch_bounds__(TPB) void strat_init(unsigned* __restrict__ out_enc, int n) {
    int i = blockIdx.x * TPB + threadIdx.x;
    if (i < n) out_enc[i] = ENC_NEG_INF;
}

__global__ __launch_bounds__(TPB) void strat_main_atomic(
    const float* __restrict__ values, const int* __restrict__ labels,
    unsigned* __restrict__ out_enc, int B, int N, int C, int T) {
    __shared__ unsigned acc[ROWS * FCPAD];
    const int tid  = threadIdx.x;
    const int row0 = blockIdx.y * ROWS;
    const int rmax = min(ROWS, B - row0);

    for (int i = tid; i < ROWS * FCPAD; i += TPB) acc[i] = ENC_NEG_INF;
    __syncthreads();

    const int t = blockIdx.x;
#pragma unroll
    for (int e = 0; e < 4; ++e) {
        const int j = t * 1024 + tid * 4 + e;
        if (j < N) {
            const int c = labels[j];
            for (int r = 0; r < rmax; ++r)
                atomicMax(&acc[r * FCPAD + c],
                          encf(values[(size_t)(row0 + r) * N + j]));
        }
    }
    __syncthreads();
    for (int i = tid; i < rmax * C; i += TPB) {
        const int r = i / C, c = i - r * C;
        atomicMax(&out_enc[(size_t)(row0 + r) * C + c], acc[r * FCPAD + c]);
    }
}

__global__ __launch_bounds__(TPB) void strat_decode(unsigned* __restrict__ buf, int n) {
    int i = blockIdx.x * TPB + threadIdx.x;
    if (i < n) {
        float f = dec32(buf[i]);
        ((float*)buf)[i] = f;
    }
}

// ---------------------------------------------------------------------------

extern "C" void kernel_launch(void* const* d_in, const int* in_sizes, int n_in,
                              void* d_out, int out_size, void* d_ws, size_t ws_size,
                              hipStream_t stream) {
    const float* values = (const float*)d_in[0];
    const int*   labels = (const int*)d_in[1];
    const int N  = in_sizes[1];
    const int B  = in_sizes[0] / N;
    const int C  = out_size / B;
    const int BC = B * C;

    const int S    = SMAX;
    const int SPAN = (((N + S - 1) / S) + 3) & ~3;   // 4-aligned span
    const int CPAD = ((C + 31) / 32) * 32 + 1;       // 129 for C=100

    // d_ws layout: [labels8: N bytes][align 256][part: S*BC u32]
    const size_t part_off   = ((size_t)N + 255) & ~(size_t)255;
    const size_t part_bytes = (size_t)S * BC * sizeof(unsigned);
    const size_t lds        = (size_t)4 * CPAD * sizeof(unsigned);

    const bool main_ok = (C <= 128) && (part_off + part_bytes <= ws_size) &&
                         ((size_t)S * SPAN >= (size_t)N);

    if (main_ok) {
        unsigned char* l8   = (unsigned char*)d_ws;
        unsigned*      part = (unsigned*)((char*)d_ws + part_off);

        strat_lab8<<<(N + TPBS - 1) / TPBS, TPBS, 0, stream>>>(labels, l8, N);

        strat_stream<<<S * B, TPBS, lds, stream>>>(
            values, l8, part, B, N, C, S, SPAN, CPAD);

        strat_red<<<(BC + TPBS - 1) / TPBS, TPBS, 0, stream>>>(
            part, (float*)d_out, BC, S);
    } else {
        unsigned* out_enc = (unsigned*)d_out;
        const int init_blocks = (out_size + TPB - 1) / TPB;
        strat_init<<<init_blocks, TPB, 0, stream>>>(out_enc, out_size);
        dim3 grid((N + 1023) / 1024, (B + ROWS - 1) / ROWS);
        strat_main_atomic<<<grid, TPB, 0, stream>>>(values, labels, out_enc, B, N, C,
                                                    (N + 1023) / 1024);
        strat_decode<<<init_blocks, TPB, 0, stream>>>(out_enc, out_size);
    }
}